// Round 22
// baseline (665.873 us; speedup 1.0000x reference)
//
#include <hip/hip_runtime.h>

#define H 181
#define T_LEN 1024
#define BB 4             // batch rows per block
#define NBLK 256         // 256 * 4 = 1024; one block per CU (LDS-pinned)
#define NTHR 768         // 12 waves, 3 per SIMD (measured-best structure)
#define KT3 3            // k-tiles of 64 -> 192 >= 181
#define FRAGB 1024       // bytes per kt fragment (64 lanes x 16 B)
#define PST 192          // unit stride (wsc, FC)
#define XSTR 1027        // x_s stride (odd -> broadcast reads conflict-free)

typedef __attribute__((ext_vector_type(4))) int   intx4;
typedef __attribute__((ext_vector_type(2))) float floatx2;

#define LOG2E 1.4426950408889634f
// Schraudolph exp2 (balanced sawtooth, |rel err| <= ~3%), clamped
#define SCH_C  1064992506.0f
#define SCH_LO 897220352.0f
#define SCH_HI 1182433024.0f

__device__ __forceinline__ float exp2_fast(float g) {
    float s = fmaf(g, 8388608.0f, SCH_C);
    s = fminf(fmaxf(s, SCH_LO), SCH_HI);
    return __uint_as_float((unsigned)s);
}
__device__ __forceinline__ float rcpf(float x)   { return __builtin_amdgcn_rcpf(x); }
__device__ __forceinline__ float exp2hw(float x) { return __builtin_amdgcn_exp2f(x); }

// R29 == R27 resubmit (broker timeout 2x; never measured).
// R27: R26 base (657.8us best; LDS-only barrier kept) + VALU-issue cuts.
// R26 post-mortem: vmcnt-drain removal = only ~2% -> scratch spill fully
// exonerated (reloads latency-hidden). VALUBusy 46% = ~710cy/SIMD/step vs
// ~210cy static count -> compiler per-step overhead. Two bit-identical cuts:
// (1) hoisted Z = {0,0,0,0} as MFMA C-operand: D!=C form, acc zero-init
//     happens ONCE instead of ~12 accvgpr/mov per wave PER STEP;
// (2) packed f32 (v_pk_fma/add/mul) for the r/z gate pair: (pR,pZ),(gr,gz),
//     (dR,dZ),(rr,zz) as float2 via __builtin_elementwise_fma -> ~4 fewer
//     VALU insts/wave/step.
// Numerics bit-identical (same IEEE fma/add/mul ops, same order).
// Adjudication: dur 605-635 = zero-init was real; 645-658 = only pk landed
// (then: disasm inventory BEFORE more VALU theories); >665 = revert R26;
// absmax != 0.0078125 = reasoning wrong, reject regardless of speed.
__device__ __forceinline__ float row_scale(const float* wrow, bool mv) {
    float rm = 0.0f;
    if (mv) for (int k = 0; k < H; ++k) rm = fmaxf(rm, fabsf(wrow[k]));
    return (rm > 1e-30f) ? rm * (1.0f / 127.0f) : 1.0f;
}

__device__ __forceinline__ intx4 build_frag(const float* wrow, float invs,
                                            bool mv, int kt, int q) {
    intx4 frag;
    #pragma unroll
    for (int w = 0; w < 4; ++w) {
        int dw = 0;
        #pragma unroll
        for (int e = 0; e < 4; ++e) {
            int k = kt * 64 + q * 16 + w * 4 + e;
            float v = (mv && k < H) ? wrow[k] * invs : 0.0f;
            v = fminf(fmaxf(rintf(v), -127.0f), 127.0f);
            int iv = (int)v;
            dw |= (iv & 255) << (8 * e);
        }
        frag[w] = dw;
    }
    return frag;
}

__launch_bounds__(NTHR, 3)
__global__ void gru_i8(const float* __restrict__ x,
                       const float* __restrict__ w_ih,
                       const float* __restrict__ w_hh,
                       const float* __restrict__ b_ih,
                       const float* __restrict__ b_hh,
                       const float* __restrict__ w_fc,
                       const float* __restrict__ b_fc,
                       float* __restrict__ out) {
    __shared__ __align__(16) char  hfr_s[2 * KT3 * FRAGB];  // 6 KB i8 h dbuf
    __shared__ __align__(16) float x_s[BB * XSTR];          // 16 KB x; reused for FC
    __shared__ float wsc_s[3 * PST];                        // w_hh row scales
    __shared__ volatile char pad_s[57344];                  // total > 80 KB: pin 1 block/CU

    const int tid  = threadIdx.x;
    const int jt   = tid >> 6;          // wave = unit tile 0..11
    const int lane = tid & 63;
    const int col  = lane & 15;
    const int q    = lane >> 4;
    const int b0   = blockIdx.x * BB;
    if (tid == 0) pad_s[0] = 0;

    // ---- A fragments: per-row int8 w_hh, 3 gates x 3 kt, 9 NAMED regs ----
    const int  mu = jt * 16 + col;
    const bool mv = (mu < H);
    const float* wrowR = w_hh + (size_t)(0 * H + (mv ? mu : 0)) * H;
    const float* wrowZ = w_hh + (size_t)(1 * H + (mv ? mu : 0)) * H;
    const float* wrowN = w_hh + (size_t)(2 * H + (mv ? mu : 0)) * H;
    const float sR = row_scale(wrowR, mv);
    const float sZ = row_scale(wrowZ, mv);
    const float sN = row_scale(wrowN, mv);
    const float iR = 1.0f / sR, iZ = 1.0f / sZ, iN = 1.0f / sN;
    const intx4 afR0 = build_frag(wrowR, iR, mv, 0, q);
    const intx4 afR1 = build_frag(wrowR, iR, mv, 1, q);
    const intx4 afR2 = build_frag(wrowR, iR, mv, 2, q);
    const intx4 afZ0 = build_frag(wrowZ, iZ, mv, 0, q);
    const intx4 afZ1 = build_frag(wrowZ, iZ, mv, 1, q);
    const intx4 afZ2 = build_frag(wrowZ, iZ, mv, 2, q);
    const intx4 afN0 = build_frag(wrowN, iN, mv, 0, q);
    const intx4 afN1 = build_frag(wrowN, iN, mv, 1, q);
    const intx4 afN2 = build_frag(wrowN, iN, mv, 2, q);
    if (q == 0) {
        wsc_s[0 * PST + mu] = sR;
        wsc_s[1 * PST + mu] = sZ;
        wsc_s[2 * PST + mu] = sN;
    }

    // ---- stage x (stride 1027); zero h frag buffers ----
    for (int i = tid; i < BB * T_LEN; i += NTHR) {
        int bb = i >> 10, t = i & 1023;
        x_s[bb * XSTR + t] = x[(size_t)b0 * T_LEN + i];
    }
    {
        int* hz = (int*)hfr_s;
        for (int i = tid; i < 2 * KT3 * FRAGB / 4; i += NTHR) hz[i] = 0;
    }
    __syncthreads();   // wsc_s ready (full barrier; prologue only)

    // ---- dense per-lane identity after DPP redistribute ----
    const int  rr4 = (col >> 2) & 3;       // reg index this lane receives
    const int  b   = col & 3;              // batch
    const int  u   = jt * 16 + q * 4 + rr4;  // unit
    const bool jv  = (u < H);
    const float dqR = -LOG2E * wsc_s[0 * PST + u] * (1.0f / 127.0f);
    const float dqZ = -LOG2E * wsc_s[1 * PST + u] * (1.0f / 127.0f);
    const float dqN =  2.0f * LOG2E * wsc_s[2 * PST + u] * (1.0f / 127.0f);
    const float baseR = jv ? -LOG2E * (b_ih[u] + b_hh[u])             : 0.0f;
    const float baseZ = jv ? -LOG2E * (b_ih[H + u] + b_hh[H + u])     : 0.0f;
    const float baseN = jv ?  2.0f * LOG2E * b_hh[2 * H + u]          : 0.0f;
    const float wrS = jv ? -LOG2E * w_ih[u]                : 0.0f;
    const float wzS = jv ? -LOG2E * w_ih[H + u]            : 0.0f;
    const float wnS = jv ?  2.0f * LOG2E * w_ih[2 * H + u] : 0.0f;
    const float bnI = jv ?  2.0f * LOG2E * b_ih[2 * H + u] : 0.0f;
    // packed r/z constants (x = R-gate, y = Z-gate)
    const floatx2 dqRZ   = {dqR, dqZ};
    const floatx2 baseRZ = {baseR, baseZ};
    const floatx2 wRZ    = {wrS, wzS};
    const floatx2 one2   = {1.0f, 1.0f};
    // per-lane byte slot in the fragment layout (this lane's unit u, batch b)
    const int wboff8 = (jt >> 2) * FRAGB + (((jt & 3) * 16 + b) * 16) + q * 4 + rr4;
    const int rbase = lane * 16;

    // Hoisted zero accumulator: first MFMA of each chain uses Z as C (D!=C),
    // so the acc zero-init happens once here, not per step.
    const intx4 Z = {0, 0, 0, 0};

    float h = 0.0f;

// LDS-only barrier: ds_write_b8 visibility needs lgkmcnt(0)+s_barrier only;
// scratch spill traffic (vmcnt) is lane-private and floats across steps.
#define LDS_BARRIER() do {                                                    \
    __builtin_amdgcn_sched_barrier(0);                                        \
    asm volatile("s_waitcnt lgkmcnt(0)" ::: "memory");                        \
    __builtin_amdgcn_s_barrier();                                             \
    __builtin_amdgcn_sched_barrier(0);                                        \
} while (0)

// One GRU step: macro (no lambda -> nothing address-taken).
#define STEP(rb, wb, t_) do {                                                 \
    intx4 bf0 = *(const intx4*)((rb) + 0 * FRAGB + rbase);                    \
    intx4 bf1 = *(const intx4*)((rb) + 1 * FRAGB + rbase);                    \
    intx4 bf2 = *(const intx4*)((rb) + 2 * FRAGB + rbase);                    \
    intx4 aR = __builtin_amdgcn_mfma_i32_16x16x64_i8(afR0, bf0, Z, 0, 0, 0);  \
    intx4 aZ = __builtin_amdgcn_mfma_i32_16x16x64_i8(afZ0, bf0, Z, 0, 0, 0);  \
    intx4 aN = __builtin_amdgcn_mfma_i32_16x16x64_i8(afN0, bf0, Z, 0, 0, 0);  \
    aR = __builtin_amdgcn_mfma_i32_16x16x64_i8(afR1, bf1, aR, 0, 0, 0);       \
    aZ = __builtin_amdgcn_mfma_i32_16x16x64_i8(afZ1, bf1, aZ, 0, 0, 0);       \
    aN = __builtin_amdgcn_mfma_i32_16x16x64_i8(afN1, bf1, aN, 0, 0, 0);       \
    aR = __builtin_amdgcn_mfma_i32_16x16x64_i8(afR2, bf2, aR, 0, 0, 0);       \
    aZ = __builtin_amdgcn_mfma_i32_16x16x64_i8(afZ2, bf2, aZ, 0, 0, 0);       \
    aN = __builtin_amdgcn_mfma_i32_16x16x64_i8(afN2, bf2, aN, 0, 0, 0);       \
    int vR = aR[0], vZ = aZ[0], vN = aN[0];                                   \
    vR = __builtin_amdgcn_update_dpp(vR, aR[1], 0x114, 0xF, 0x2, false);      \
    vR = __builtin_amdgcn_update_dpp(vR, aR[2], 0x118, 0xF, 0x4, false);      \
    vR = __builtin_amdgcn_update_dpp(vR, aR[3], 0x11C, 0xF, 0x8, false);      \
    vZ = __builtin_amdgcn_update_dpp(vZ, aZ[1], 0x114, 0xF, 0x2, false);      \
    vZ = __builtin_amdgcn_update_dpp(vZ, aZ[2], 0x118, 0xF, 0x4, false);      \
    vZ = __builtin_amdgcn_update_dpp(vZ, aZ[3], 0x11C, 0xF, 0x8, false);      \
    vN = __builtin_amdgcn_update_dpp(vN, aN[1], 0x114, 0xF, 0x2, false);      \
    vN = __builtin_amdgcn_update_dpp(vN, aN[2], 0x118, 0xF, 0x4, false);      \
    vN = __builtin_amdgcn_update_dpp(vN, aN[3], 0x11C, 0xF, 0x8, false);      \
    floatx2 v2 = {(float)vR, (float)vZ};                                      \
    floatx2 p2 = __builtin_elementwise_fma(v2, dqRZ, baseRZ);                 \
    float pN = fmaf((float)vN, dqN, baseN);                                   \
    float xv = x_s[b * XSTR + (t_)];                                          \
    floatx2 x2 = {xv, xv};                                                    \
    floatx2 g2 = __builtin_elementwise_fma(x2, wRZ, p2);                      \
    float er = exp2_fast(g2.x);                                               \
    float ez = exp2hw(fminf(g2.y, 14.0f));                                    \
    floatx2 e2 = {er, ez};                                                    \
    floatx2 d2 = e2 + one2;                                                   \
    float qq = rcpf(d2.x * d2.y);                                             \
    floatx2 q2 = {qq, qq};                                                    \
    floatx2 sw = {d2.y, d2.x};                                                \
    floatx2 rz = q2 * sw;   /* rz.x = rr, rz.y = zz */                        \
    float gn = fmaf(rz.x, pN, fmaf(xv, wnS, bnI));                            \
    float en = exp2hw(fminf(gn, 30.0f));                                      \
    float nn = fmaf(-2.0f, rcpf(1.0f + en), 1.0f);                            \
    h = fmaf(rz.y, h - nn, nn);                                               \
    int hq = __float_as_int(fmaf(h, 127.0f, 12582912.0f));                    \
    *(char*)((wb) + wboff8) = (char)hq;                                       \
    LDS_BARRIER();                                                            \
} while (0)

    char* buf0 = hfr_s;
    char* buf1 = hfr_s + KT3 * FRAGB;
    for (int t = 0; t < T_LEN; t += 2) {
        STEP(buf0, buf1, t);
        STEP(buf1, buf0, t + 1);
    }
#undef STEP
#undef LDS_BARRIER

    // ---- final FC: publish h (f32) into x_s (x done), 40 lanes reduce ----
    __syncthreads();
    if (u < PST) x_s[b * PST + u] = h;
    __syncthreads();
    if (tid < BB * 10) {
        int bb = tid / 10, c = tid % 10;
        float acc = b_fc[c];
        for (int k = 0; k < H; ++k)
            acc = fmaf(x_s[bb * PST + k], w_fc[c * H + k], acc);
        out[(b0 + bb) * 10 + c] = acc;
    }
}

extern "C" void kernel_launch(void* const* d_in, const int* in_sizes, int n_in,
                              void* d_out, int out_size, void* d_ws, size_t ws_size,
                              hipStream_t stream) {
    const float* x    = (const float*)d_in[0];
    const float* w_ih = (const float*)d_in[1];
    const float* w_hh = (const float*)d_in[2];
    const float* b_ih = (const float*)d_in[3];
    const float* b_hh = (const float*)d_in[4];
    const float* w_fc = (const float*)d_in[5];
    const float* b_fc = (const float*)d_in[6];
    float* out = (float*)d_out;

    gru_i8<<<NBLK, NTHR, 0, stream>>>(x, w_ih, w_hh, b_ih, b_hh, w_fc, b_fc, out);
}